// Round 10
// baseline (2849.133 us; speedup 1.0000x reference)
//
#include <hip/hip_runtime.h>
#include <hip/hip_bf16.h>
#include <math.h>

#define EMBC   192
#define NLAY   6
#define IMGC   224
#define FMAPC  56
#define NNODE  3136      // 56*56
#define NBATCH 8
#define BNODES 25088     // NBATCH*NNODE
#define KNNE   8
#define NT     32        // nodes per tile
#define RSQRT2 0.70710678118654752f

__device__ __forceinline__ float sigm(float x){ return 1.0f/(1.0f+__expf(-x)); }

// ---------------- weight repack kernels (run once per launch, tiny) ----------------
// [L][64ch][K][3] -> [L][wave=ch/8][K][8ch][3]
__global__ void k_repackw(const float* __restrict__ src, float* __restrict__ dst, int K){
  int l = blockIdx.y;
  size_t S = (size_t)64*K*3;
  int t = blockIdx.x*256 + threadIdx.x;
  if(t < (int)S){
    int j = t % 3; int r = t / 3;
    int ci = r % 8; int m = (r / 8) % K; int wid = r / (8*K);
    dst[l*S + (((size_t)wid*K + m)*8 + ci)*3 + j] =
      src[l*S + ((size_t)(wid*8+ci)*K + m)*3 + j];
  }
}
// [R][K] -> [K][R]
__global__ void k_repack1(const float* __restrict__ src, float* __restrict__ dst,
                          int R, int K){
  int t = blockIdx.x*256 + threadIdx.x;
  if(t < R*K){
    int m = t % K, r = t / K;
    dst[m*R + r] = src[r*K + m];
  }
}

// ---------------- K0: transpose stem_g / (stem_b+pos) to [n][c] ----------------
__global__ void k_tr(const float* __restrict__ g, const float* __restrict__ sb,
                     const float* __restrict__ pe, float* __restrict__ g2,
                     float* __restrict__ pb2){
  int n = blockIdx.x; int c = threadIdx.x;
  g2[n*EMBC + c]  = g[c*NNODE + n];
  pb2[n*EMBC + c] = sb[c*NNODE + n] + pe[c*NNODE + n];
}

// ---------------- K1: stem conv (4x4 stride 4) + LN partial sums ----------------
__global__ __launch_bounds__(256) void k_conv(const float* __restrict__ x,
    const float* __restrict__ cw, const float* __restrict__ cb,
    float* __restrict__ y0, float* __restrict__ parts){
  __shared__ float xs[2688];
  __shared__ float wsh[9216];
  __shared__ float red[512];
  int blk = blockIdx.x; int b = blk / FMAPC; int ph = blk % FMAPC;
  int tid = threadIdx.x;
  for(int t = tid; t < 9216; t += 256) wsh[t] = cw[t];
  for(int t = tid; t < 2688; t += 256){
    int r = t / IMGC; int w = t % IMGC;
    int ci = r >> 2, kh = r & 3;
    xs[t] = x[((size_t)(b*3 + ci)*IMGC + (ph*4 + kh))*IMGC + w];
  }
  __syncthreads();
  float s1 = 0.f, s2 = 0.f;
  for(int oi = tid; oi < FMAPC*EMBC; oi += 256){
    int pw = oi / EMBC; int c = oi % EMBC;
    float acc = cb[c];
    const float4* wv4 = (const float4*)(wsh + c*48);
    #pragma unroll
    for(int r = 0; r < 12; ++r){
      float4 xv = *((const float4*)(xs + r*IMGC + pw*4));
      float4 wv = wv4[r];
      acc += xv.x*wv.x + xv.y*wv.y + xv.z*wv.z + xv.w*wv.w;
    }
    y0[((size_t)(b*NNODE + ph*FMAPC + pw))*EMBC + c] = acc;
    s1 += acc; s2 += acc*acc;
  }
  red[tid] = s1; red[256+tid] = s2;
  __syncthreads();
  for(int st = 128; st > 0; st >>= 1){
    if(tid < st){ red[tid] += red[tid+st]; red[256+tid] += red[256+tid+st]; }
    __syncthreads();
  }
  if(tid == 0){ parts[blk*2] = red[0]; parts[blk*2+1] = red[256]; }
}

// ---------------- K2: finalize per-batch LN stats ----------------
__global__ void k_stats(const float* __restrict__ parts, float* __restrict__ stats){
  int b = threadIdx.x;
  if(b < NBATCH){
    float S = 0.f, Q = 0.f;
    for(int j = 0; j < FMAPC; ++j){ S += parts[(b*FMAPC+j)*2]; Q += parts[(b*FMAPC+j)*2+1]; }
    float cnt = (float)(EMBC*NNODE);
    float mu = S/cnt;
    float var = Q/cnt - mu*mu;
    stats[b*2] = mu; stats[b*2+1] = rsqrtf(var + 1e-5f);
  }
}

// ---------------- K3: LN + pos + embed + mvlin_flat(in_W) -> x_mv ----------------
__global__ __launch_bounds__(256,2) void k_embed(const float* __restrict__ y0,
    const float* __restrict__ stats, const float* __restrict__ g2,
    const float* __restrict__ pb2, const float* __restrict__ inWp,
    const float* __restrict__ inb, const float* __restrict__ coords,
    float* __restrict__ xmv){
  __shared__ float fs[64*193];
  int tid = threadIdx.x, lane = tid & 63;
  int wid = __builtin_amdgcn_readfirstlane(tid >> 6);
  int ch0 = wid << 4;
  int bid = blockIdx.x;
  int blk = (bid & 7)*49 + (bid >> 3);   // 392 = 8*49, XCD-contiguous
  int p0 = blk * 64;
  int b = p0 / NNODE; int n0 = p0 - b*NNODE;
  float mu = stats[b*2], rstd = stats[b*2+1];
  for(int t = tid; t < 64*192; t += 256){
    int n = t / 192, c = t - n*192;
    int nn = n0 + n;
    fs[n*193 + c] = (y0[(size_t)(p0+n)*192 + c] - mu)*rstd*g2[nn*192+c] + pb2[nn*192+c];
  }
  __syncthreads();
  float acc[16];
  #pragma unroll
  for(int ci = 0; ci < 16; ++ci) acc[ci] = 0.f;
  #pragma unroll 2
  for(int m = 0; m < 192; ++m){
    float xm = fs[lane*193 + m];
    const float* wp = inWp + m*64 + ch0;
    #pragma unroll
    for(int ci = 0; ci < 16; ++ci) acc[ci] += wp[ci]*xm;
  }
  float cx = coords[(n0+lane)*2], cy = coords[(n0+lane)*2+1];
  #pragma unroll
  for(int ci = 0; ci < 16; ++ci){
    int ch = ch0 + ci;
    float wc = inWp[192*64 + ch];
    float4 v; v.x = acc[ci] + inb[ch]; v.y = wc*cx; v.z = wc*cy; v.w = 0.f;
    *((float4*)(xmv + ((size_t)(p0+lane)*64 + ch)*4)) = v;
  }
}

// ============ tile helpers (NT=32, 512 threads) ============
// xs layout: row n of 256 floats; element (n,m,bi) at xs[(n<<8)+(((m+n)&63)<<2)+bi]
// register-staged activation tile: issue loads early, ds_write late (T14)
__device__ __forceinline__ void xload(float4 (&r)[4], const float* __restrict__ g,
                                      int p0, int tid){
  #pragma unroll
  for(int i = 0; i < 4; ++i){
    int t = tid + i*512;               // [0,2048)
    int nn = t >> 6, m = t & 63;
    r[i] = *((const float4*)(g + (((size_t)(p0+nn))<<8) + (m<<2)));
  }
}
__device__ __forceinline__ void xwrite(float* xs, const float4 (&r)[4], int tid){
  #pragma unroll
  for(int i = 0; i < 4; ++i){
    int t = tid + i*512;
    int nn = t >> 6, m = t & 63;
    *((float4*)(xs + (nn<<8) + (((m + nn)&63)<<2))) = r[i];
  }
}
__device__ __forceinline__ void copyout(const float* xs, float* __restrict__ g,
                                        int p0, int tid){
  #pragma unroll
  for(int t = tid; t < NT*64; t += 512){
    int n = t >> 6, m = t & 63;
    float4 v = *((const float4*)(xs + (n<<8) + (((m + n)&63)<<2)));
    *((float4*)(g + (((size_t)(p0+n))<<8) + (m<<2))) = v;
  }
}
// register-staged weight window (48KB): 6 float4 per thread
__device__ __forceinline__ void wload(float4 (&r)[6], const float* __restrict__ Wp,
                                      int K, int moff, int tid){
  #pragma unroll
  for(int i = 0; i < 6; ++i){
    int t = tid + i*512;               // [0,3072)
    int c = t / 384, q = t - c*384;
    r[i] = ((const float4*)(Wp + ((size_t)(c*K + moff)*24)))[q];
  }
}
__device__ __forceinline__ void wwrite(float* wst, const float4 (&r)[6], int tid){
  #pragma unroll
  for(int i = 0; i < 6; ++i)
    ((float4*)wst)[tid + i*512] = r[i];
}
// matmul pass: acc[4ch][4bl] over 64 m; wb = wid*1536 + s*12
__device__ __forceinline__ void mm4(float (&acc)[4][4], const float* __restrict__ wst,
                                    const float* __restrict__ xrow, int wb, int n){
  #pragma unroll 4
  for(int m = 0; m < 64; ++m){
    float4 xv = *((const float4*)(xrow + (((m + n)&63)<<2)));
    const float* wp = wst + wb + m*24;
    float4 a = *((const float4*)wp);
    float4 b = *((const float4*)(wp+4));
    float4 c = *((const float4*)(wp+8));
    acc[0][0]+=a.x*xv.x; acc[0][1]+=a.y*xv.y; acc[0][2]+=a.y*xv.z; acc[0][3]+=a.z*xv.w;
    acc[1][0]+=a.w*xv.x; acc[1][1]+=b.x*xv.y; acc[1][2]+=b.x*xv.z; acc[1][3]+=b.y*xv.w;
    acc[2][0]+=b.z*xv.x; acc[2][1]+=b.w*xv.y; acc[2][2]+=b.w*xv.z; acc[2][3]+=c.x*xv.w;
    acc[3][0]+=c.y*xv.x; acc[3][1]+=c.z*xv.y; acc[3][2]+=c.z*xv.z; acc[3][3]+=c.w*xv.w;
  }
}
#define ZERO44(A) { _Pragma("unroll") for(int _i=0;_i<4;++_i) _Pragma("unroll") for(int _j=0;_j<4;++_j) A[_i][_j]=0.f; }

// ---------------- K_sgp0: input sgp (mode 0) + fused z0 = eW0 * h ----------------
__global__ __launch_bounds__(512,4) void k_sgp0(const float* __restrict__ src,
    float* __restrict__ h, float* __restrict__ zout,
    const float* __restrict__ Wlp, const float* __restrict__ bl,
    const float* __restrict__ Wrp, const float* __restrict__ na,
    const float* __restrict__ gw, const float* __restrict__ zWp){
  __shared__ float xs[NT*256];    // 32 KB
  __shared__ float wst[12288];    // 48 KB
  int tid = threadIdx.x, lane = tid & 63;
  int wid = __builtin_amdgcn_readfirstlane(tid >> 6);
  int n = lane & 31, s = lane >> 5;
  int ch0 = (wid<<3) + s*4;
  int wb  = wid*1536 + s*12;
  int bid = blockIdx.x;
  int blk = (bid & 7)*98 + (bid >> 3);   // 784 = 8*98, XCD-contiguous
  int p0 = blk * NT;
  const float* xrow = xs + (n<<8);
  float4 wr_[6]; float4 xr_[4];
  wload(wr_, Wlp, 64, 0, tid);
  xload(xr_, src, p0, tid);
  wwrite(wst, wr_, tid);
  xwrite(xs, xr_, tid);
  __syncthreads();                       // B1
  wload(wr_, Wrp, 64, 0, tid);
  float accl[4][4], accr[4][4];
  ZERO44(accl); ZERO44(accr);
  mm4(accl, wst, xrow, wb, n);
  __syncthreads();                       // B2
  wwrite(wst, wr_, tid);
  __syncthreads();                       // B3
  wload(wr_, zWp, 64, 0, tid);
  mm4(accr, wst, xrow, wb, n);
  // epilogue (mode 0)
  float out[4][4];
  #pragma unroll
  for(int ci = 0; ci < 4; ++ci){
    int ch = ch0 + ci;
    float yr0 = accr[ci][0], yr1 = accr[ci][1], yr2 = accr[ci][2], yr3 = accr[ci][3];
    float na0 = sigm(na[ch*3]), na1 = sigm(na[ch*3+1]), na2 = sigm(na[ch*3+2]);
    float d0 = na0*(sqrtf(yr0*yr0 + 1e-12f) - 1.f) + 1.f + 1e-6f;
    float d1 = na1*(sqrtf(yr1*yr1 + yr2*yr2 + 1e-12f) - 1.f) + 1.f + 1e-6f;
    float d2 = na2*(sqrtf(yr3*yr3 + 1e-12f) - 1.f) + 1.f + 1e-6f;
    float xq0 = yr0/d0, xq1 = yr1/d1, xq2 = yr2/d1, xq3 = yr3/d2;
    float4 xv = *((const float4*)(xrow + (((ch + n)&63)<<2)));   // x_mv[n][ch]
    const float* gwp = gw + ch*10;
    float gp0 = gwp[0]*xv.x*xq0 + gwp[3]*(xv.y*xq1 + xv.z*xq2) + gwp[7]*xv.w*xq3;
    float gp1 = gwp[1]*xv.x*xq1 + gwp[4]*xv.y*xq0 - gwp[5]*xv.z*xq3 - gwp[8]*xv.w*xq2;
    float gp2 = gwp[1]*xv.x*xq2 + gwp[4]*xv.z*xq0 + gwp[5]*xv.y*xq3 + gwp[8]*xv.w*xq1;
    float gp3 = gwp[2]*xv.x*xq3 + gwp[6]*(xv.y*xq2 - xv.z*xq1) - gwp[9]*xv.w*xq0;
    out[ci][0] = (accl[ci][0] + bl[ch] + gp0)*RSQRT2;
    out[ci][1] = (accl[ci][1] + gp1)*RSQRT2;
    out[ci][2] = (accl[ci][2] + gp2)*RSQRT2;
    out[ci][3] = (accl[ci][3] + gp3)*RSQRT2;
  }
  __syncthreads();                       // B4
  #pragma unroll
  for(int ci = 0; ci < 4; ++ci){
    int ch = ch0 + ci;
    float4 v; v.x=out[ci][0]; v.y=out[ci][1]; v.z=out[ci][2]; v.w=out[ci][3];
    *((float4*)(xs + (n<<8) + (((ch + n)&63)<<2))) = v;
  }
  __syncthreads();                       // B5
  copyout(xs, h, p0, tid);
  wwrite(wst, wr_, tid);
  __syncthreads();                       // B6
  float zA[4][4];
  ZERO44(zA);
  mm4(zA, wst, xrow, wb, n);
  __syncthreads();                       // B7
  #pragma unroll
  for(int ci = 0; ci < 4; ++ci){
    int ch = ch0 + ci;
    float4 v; v.x=zA[ci][0]; v.y=zA[ci][1]; v.z=zA[ci][2]; v.w=zA[ci][3];
    *((float4*)(xs + (n<<8) + (((ch + n)&63)<<2))) = v;
  }
  __syncthreads();                       // B8
  copyout(xs, zout, p0, tid);
}

// ---------------- K_layer: edge-agg + nu + sgp(+silu,+residual) + next z ----------------
__global__ __launch_bounds__(512,4) void k_layer(
    float* __restrict__ h, const float* __restrict__ z,
    float* __restrict__ zout, const int* __restrict__ cols,
    const float* __restrict__ eb, const float* __restrict__ sa,
    const float* __restrict__ sb,
    const float* __restrict__ nWp, const float* __restrict__ nb,
    const float* __restrict__ Wlp, const float* __restrict__ bl,
    const float* __restrict__ Wrp, const float* __restrict__ na,
    const float* __restrict__ gw, const float* __restrict__ aa,
    const float* __restrict__ ab,
    const float* __restrict__ zWp, int mode){
  __shared__ float xs[NT*256];    // 32 KB
  __shared__ float wst[12288];    // 48 KB
  int tid = threadIdx.x, lane = tid & 63;
  int wid = __builtin_amdgcn_readfirstlane(tid >> 6);
  int n = lane & 31, s = lane >> 5;
  int ch0 = (wid<<3) + s*4;
  int wb  = wid*1536 + s*12;
  int bid = blockIdx.x;
  int blk = (bid & 7)*98 + (bid >> 3);   // 784 = 8*98, XCD-contiguous
  int p0 = blk * NT;
  const float* xrow = xs + (n<<8);
  // issue first-phase staging loads; latency hidden under edge-agg
  float4 wr_[6]; float4 xr_[4];
  wload(wr_, nWp, 128, 0, tid);          // nu-lo
  xload(xr_, h, p0, tid);                // h tile
  // ---- phase A: edge aggregation; wave wid owns nodes p0+wid*4..+3; lane = ch
  float ag[4][4];
  {
    int ch = lane;
    float ebv = eb[ch];
    float a0 = sa[ch*3], a1 = sa[ch*3+1], a2 = sa[ch*3+2];
    float b0 = sb[ch*3], b1 = sb[ch*3+1], b2 = sb[ch*3+2];
    #pragma unroll
    for(int e = 0; e < 4; ++e){
      int p = p0 + wid*4 + e;
      float4 zo = *((const float4*)(z + ((size_t)p*64 + ch)*4));
      float ax=0.f, ay=0.f, az_=0.f, aw=0.f;
      #pragma unroll
      for(int k = 0; k < KNNE; ++k){
        int c = cols[p*KNNE + k];
        float4 zc = *((const float4*)(z + ((size_t)c*64 + ch)*4));
        float d0 = zo.x - zc.x + ebv;
        float d1 = zo.y - zc.y;
        float d2 = zo.z - zc.z;
        float d3 = zo.w - zc.w;
        float g0 = sigm(a0*d0 + b0);
        float g1 = sigm(a1*(d1*d1 + d2*d2) + b1);
        float g2v = sigm(a2*(d3*d3) + b2);
        ax += g0*d0; ay += g1*d1; az_ += g1*d2; aw += g2v*d3;
      }
      ag[e][0]=ax; ag[e][1]=ay; ag[e][2]=az_; ag[e][3]=aw;
    }
  }
  // commit staged h + nu-lo
  wwrite(wst, wr_, tid);
  xwrite(xs, xr_, tid);
  __syncthreads();                       // B1
  wload(wr_, nWp, 128, 64, tid);         // nu-hi issue (hidden under mm)
  float nuA[4][4];
  ZERO44(nuA);
  mm4(nuA, wst, xrow, wb, n);            // nu pass1 (h part)
  float hrA[4][4];
  if(mode == 2){
    #pragma unroll
    for(int ci = 0; ci < 4; ++ci){
      int ch = ch0 + ci;
      float4 v0 = *((const float4*)(xrow + (((ch + n)&63)<<2)));
      hrA[ci][0]=v0.x; hrA[ci][1]=v0.y; hrA[ci][2]=v0.z; hrA[ci][3]=v0.w;
    }
  }
  __syncthreads();                       // B2
  // agg overwrites xs; commit nu-hi
  #pragma unroll
  for(int e = 0; e < 4; ++e){
    int nn = wid*4 + e;
    float4 v; v.x=ag[e][0]; v.y=ag[e][1]; v.z=ag[e][2]; v.w=ag[e][3];
    *((float4*)(xs + (nn<<8) + (((lane + nn)&63)<<2))) = v;   // lane = ch
  }
  wwrite(wst, wr_, tid);
  __syncthreads();                       // B3
  wload(wr_, Wlp, 64, 0, tid);           // Wl issue
  mm4(nuA, wst, xrow, wb, n);            // nu pass2 (agg part)
  __syncthreads();                       // B4
  // nu (with bias) -> xs; commit Wl
  #pragma unroll
  for(int ci = 0; ci < 4; ++ci){
    int ch = ch0 + ci;
    nuA[ci][0] += nb[ch];
    float4 v; v.x=nuA[ci][0]; v.y=nuA[ci][1]; v.z=nuA[ci][2]; v.w=nuA[ci][3];
    *((float4*)(xs + (n<<8) + (((ch + n)&63)<<2))) = v;
  }
  wwrite(wst, wr_, tid);
  __syncthreads();                       // B5
  wload(wr_, Wrp, 64, 0, tid);           // Wr issue
  float accl[4][4], accr[4][4];
  ZERO44(accl); ZERO44(accr);
  mm4(accl, wst, xrow, wb, n);
  __syncthreads();                       // B6
  wwrite(wst, wr_, tid);
  __syncthreads();                       // B7
  if(zWp != nullptr) wload(wr_, zWp, 64, 0, tid);   // zW issue
  mm4(accr, wst, xrow, wb, n);
  // ---- epilogue: normalize, gp (x = nu regs), silu, residual
  float out[4][4];
  #pragma unroll
  for(int ci = 0; ci < 4; ++ci){
    int ch = ch0 + ci;
    float yr0 = accr[ci][0], yr1 = accr[ci][1], yr2 = accr[ci][2], yr3 = accr[ci][3];
    float na0 = sigm(na[ch*3]), na1 = sigm(na[ch*3+1]), na2 = sigm(na[ch*3+2]);
    float d0 = na0*(sqrtf(yr0*yr0 + 1e-12f) - 1.f) + 1.f + 1e-6f;
    float d1 = na1*(sqrtf(yr1*yr1 + yr2*yr2 + 1e-12f) - 1.f) + 1.f + 1e-6f;
    float d2 = na2*(sqrtf(yr3*yr3 + 1e-12f) - 1.f) + 1.f + 1e-6f;
    float xq0 = yr0/d0, xq1 = yr1/d1, xq2 = yr2/d1, xq3 = yr3/d2;
    float x0 = nuA[ci][0], x1 = nuA[ci][1], x2 = nuA[ci][2], x3 = nuA[ci][3];
    const float* gwp = gw + ch*10;
    float gp0 = gwp[0]*x0*xq0 + gwp[3]*(x1*xq1 + x2*xq2) + gwp[7]*x3*xq3;
    float gp1 = gwp[1]*x0*xq1 + gwp[4]*x1*xq0 - gwp[5]*x2*xq3 - gwp[8]*x3*xq2;
    float gp2 = gwp[1]*x0*xq2 + gwp[4]*x2*xq0 + gwp[5]*x1*xq3 + gwp[8]*x3*xq1;
    float gp3 = gwp[2]*x0*xq3 + gwp[6]*(x1*xq2 - x2*xq1) - gwp[9]*x3*xq0;
    float o0 = (accl[ci][0] + bl[ch] + gp0)*RSQRT2;
    float o1 = (accl[ci][1] + gp1)*RSQRT2;
    float o2 = (accl[ci][2] + gp2)*RSQRT2;
    float o3 = (accl[ci][3] + gp3)*RSQRT2;
    float g0 = sigm(aa[ch*3]*o0 + ab[ch*3]);
    float g1 = sigm(aa[ch*3+1]*(o1*o1 + o2*o2) + ab[ch*3+1]);
    float g2v = sigm(aa[ch*3+2]*(o3*o3) + ab[ch*3+2]);
    float v0 = g0*o0, v1 = g1*o1, v2 = g1*o2, v3 = g2v*o3;
    if(mode == 2){ v0 += hrA[ci][0]; v1 += hrA[ci][1]; v2 += hrA[ci][2]; v3 += hrA[ci][3]; }
    out[ci][0]=v0; out[ci][1]=v1; out[ci][2]=v2; out[ci][3]=v3;
  }
  __syncthreads();                       // B8
  #pragma unroll
  for(int ci = 0; ci < 4; ++ci){
    int ch = ch0 + ci;
    float4 v; v.x=out[ci][0]; v.y=out[ci][1]; v.z=out[ci][2]; v.w=out[ci][3];
    *((float4*)(xs + (n<<8) + (((ch + n)&63)<<2))) = v;
  }
  __syncthreads();                       // B9
  copyout(xs, h, p0, tid);
  // ---- z_next = zW * h_new
  if(zWp != nullptr){
    wwrite(wst, wr_, tid);
    __syncthreads();                     // B10
    float zA[4][4];
    ZERO44(zA);
    mm4(zA, wst, xrow, wb, n);
    __syncthreads();                     // B11
    #pragma unroll
    for(int ci = 0; ci < 4; ++ci){
      int ch = ch0 + ci;
      float4 v; v.x=zA[ci][0]; v.y=zA[ci][1]; v.z=zA[ci][2]; v.w=zA[ci][3];
      *((float4*)(xs + (n<<8) + (((ch + n)&63)<<2))) = v;
    }
    __syncthreads();                     // B12
    copyout(xs, zout, p0, tid);
  }
}

// ---------------- K9: head projection (blade 0) + per-node LN ----------------
__global__ __launch_bounds__(256,2) void k_head(const float* __restrict__ h,
    const float* __restrict__ oWp, const float* __restrict__ ob,
    const float* __restrict__ ong, const float* __restrict__ onb,
    float* __restrict__ s){
  __shared__ float hs[64*65];
  __shared__ float rr[512];
  int tid = threadIdx.x, lane = tid & 63;
  int wid = __builtin_amdgcn_readfirstlane(tid >> 6);
  int c0 = wid*48;
  int bid = blockIdx.x;
  int blk = (bid & 7)*49 + (bid >> 3);   // 392 = 8*49
  int p0 = blk * 64;
  for(int t = tid; t < 64*64; t += 256){
    int nn = t >> 6, c = t & 63;
    hs[nn*65 + c] = h[(((size_t)(p0+nn))*64 + c)*4];
  }
  __syncthreads();
  float a[48];
  #pragma unroll
  for(int ci = 0; ci < 48; ++ci) a[ci] = 0.f;
  #pragma unroll 2
  for(int m = 0; m < 64; ++m){
    float xm = hs[lane*65 + m];
    const float* wp = oWp + m*192 + c0;
    #pragma unroll
    for(int ci = 0; ci < 48; ++ci) a[ci] += wp[ci]*xm;
  }
  float s1 = 0.f, s2 = 0.f;
  #pragma unroll
  for(int ci = 0; ci < 48; ++ci){
    a[ci] += ob[c0+ci];
    s1 += a[ci]; s2 += a[ci]*a[ci];
  }
  rr[wid*64 + lane] = s1; rr[256 + wid*64 + lane] = s2;
  __syncthreads();
  float S = rr[lane] + rr[64+lane] + rr[128+lane] + rr[192+lane];
  float Q = rr[256+lane] + rr[320+lane] + rr[384+lane] + rr[448+lane];
  float mu = S*(1.0f/EMBC);
  float var = Q*(1.0f/EMBC) - mu*mu;
  float rstd = rsqrtf(var + 1e-5f);
  #pragma unroll
  for(int q = 0; q < 12; ++q){
    int c = c0 + q*4;
    float4 v;
    v.x = (a[q*4  ] - mu)*rstd*ong[c  ] + onb[c  ];
    v.y = (a[q*4+1] - mu)*rstd*ong[c+1] + onb[c+1];
    v.z = (a[q*4+2] - mu)*rstd*ong[c+2] + onb[c+2];
    v.w = (a[q*4+3] - mu)*rstd*ong[c+3] + onb[c+3];
    *((float4*)(s + (size_t)(p0+lane)*192 + c)) = v;
  }
}

// ---------------- K10: pooling (two-stage, deterministic) ----------------
__global__ void k_pool1(const float* __restrict__ s, float* __restrict__ pp){
  int blk = blockIdx.x;
  int b = blk >> 5, chunk = blk & 31;
  int c = threadIdx.x;
  float acc = 0.f;
  int n0 = chunk*98;
  for(int j = 0; j < 98; ++j) acc += s[((size_t)(b*NNODE + n0 + j))*EMBC + c];
  pp[(size_t)blk*EMBC + c] = acc;
}
__global__ void k_pool2(const float* __restrict__ pp, float* __restrict__ pooled){
  int b = blockIdx.x; int c = threadIdx.x;
  float acc = 0.f;
  for(int j = 0; j < 32; ++j) acc += pp[((size_t)(b*32 + j))*EMBC + c];
  pooled[b*EMBC + c] = acc * (1.0f/NNODE);
}

// ---------------- K11: classifier ----------------
__global__ void k_cls(const float* __restrict__ pooled, const float* __restrict__ cW,
                      const float* __restrict__ cb, float* __restrict__ out){
  int tid = threadIdx.x;
  if(tid < NBATCH*10){
    int b = tid/10, k = tid%10;
    float acc = cb[k];
    for(int c = 0; c < EMBC; ++c) acc += pooled[b*EMBC + c]*cW[k*EMBC + c];
    out[tid] = acc;
  }
}

extern "C" void kernel_launch(void* const* d_in, const int* in_sizes, int n_in,
                              void* d_out, int out_size, void* d_ws, size_t ws_size,
                              hipStream_t stream){
  const float* x      = (const float*)d_in[0];
  const float* conv_w = (const float*)d_in[1];
  const float* conv_b = (const float*)d_in[2];
  const float* stem_g = (const float*)d_in[3];
  const float* stem_b = (const float*)d_in[4];
  const float* pos_e  = (const float*)d_in[5];
  const float* coords = (const float*)d_in[6];
  const float* inW    = (const float*)d_in[7];
  const float* inb    = (const float*)d_in[8];
  const float* inWl   = (const float*)d_in[9];
  const float* inbl   = (const float*)d_in[10];
  const float* inWr   = (const float*)d_in[11];
  const float* inna   = (const float*)d_in[12];
  const float* ingw   = (const float*)d_in[13];
  const float* eg_eW  = (const float*)d_in[14];
  const float* eg_eb  = (const float*)d_in[15];
  const float* eg_sa  = (const float*)d_in[16];
  const float* eg_sb  = (const float*)d_in[17];
  const float* eg_nW  = (const float*)d_in[18];
  const float* eg_nb  = (const float*)d_in[19];
  const float* eg_Wl  = (const float*)d_in[20];
  const float* eg_bl  = (const float*)d_in[21];
  const float* eg_Wr  = (const float*)d_in[22];
  const float* eg_na  = (const float*)d_in[23];
  const float* eg_gw  = (const float*)d_in[24];
  const float* eg_aa  = (const float*)d_in[25];
  const float* eg_ab  = (const float*)d_in[26];
  const float* outW   = (const float*)d_in[27];
  const float* outb   = (const float*)d_in[28];
  const float* ong    = (const float*)d_in[29];
  const float* onb    = (const float*)d_in[30];
  const float* clsW   = (const float*)d_in[31];
  const float* clsb   = (const float*)d_in[32];
  const int*   cols   = (const int*)d_in[34];   // rows[p*8+k] == p by construction

  float* ws = (float*)d_ws;
  size_t off = 0;
  float* hbuf  = ws + off; off += (size_t)BNODES*256;   // h
  float* bigA  = ws + off; off += (size_t)BNODES*256;   // x_mv / z ping
  float* bigB  = ws + off; off += (size_t)BNODES*256;   // y0 (stem) then z pong
  float* g2    = ws + off; off += (size_t)NNODE*EMBC;
  float* pb2   = ws + off; off += (size_t)NNODE*EMBC;
  float* parts = ws + off; off += 896;
  float* stats = ws + off; off += 16;
  float* pp    = ws + off; off += 256*EMBC;
  float* pooled= ws + off; off += NBATCH*EMBC;
  // packed weights
  float* wpInW = ws + off; off += 193*64;
  float* wpOW  = ws + off; off += 64*192;
  float* wpInWl= ws + off; off += 12288;
  float* wpInWr= ws + off; off += 12288;
  float* wpEW  = ws + off; off += (size_t)NLAY*12288;
  float* wpWl  = ws + off; off += (size_t)NLAY*12288;
  float* wpWr  = ws + off; off += (size_t)NLAY*12288;
  float* wpNW  = ws + off; off += (size_t)NLAY*24576;
  float* y0    = bigB;   // stem output aliases bigB (dead before first z write)

  const int NTILE = BNODES/NT;   // 784

  // ---- weight repacks ----
  { dim3 g1((12352+255)/256); k_repack1<<<g1, 256, 0, stream>>>(inW,  wpInW, 64, 193); }
  { dim3 g1((12288+255)/256); k_repack1<<<g1, 256, 0, stream>>>(outW, wpOW, 192, 64); }
  { dim3 g3((12288+255)/256, 1); k_repackw<<<g3, 256, 0, stream>>>(inWl, wpInWl, 64); }
  { dim3 g3((12288+255)/256, 1); k_repackw<<<g3, 256, 0, stream>>>(inWr, wpInWr, 64); }
  { dim3 g3((12288+255)/256, NLAY); k_repackw<<<g3, 256, 0, stream>>>(eg_eW, wpEW, 64); }
  { dim3 g3((12288+255)/256, NLAY); k_repackw<<<g3, 256, 0, stream>>>(eg_Wl, wpWl, 64); }
  { dim3 g3((12288+255)/256, NLAY); k_repackw<<<g3, 256, 0, stream>>>(eg_Wr, wpWr, 64); }
  { dim3 g3((24576+255)/256, NLAY); k_repackw<<<g3, 256, 0, stream>>>(eg_nW, wpNW, 128); }

  k_tr   <<<NNODE, 192, 0, stream>>>(stem_g, stem_b, pos_e, g2, pb2);
  k_conv <<<NBATCH*FMAPC, 256, 0, stream>>>(x, conv_w, conv_b, y0, parts);
  k_stats<<<1, 64, 0, stream>>>(parts, stats);
  k_embed<<<BNODES/64, 256, 0, stream>>>(y0, stats, g2, pb2, wpInW, inb, coords, bigA);
  k_sgp0 <<<NTILE, 512, 0, stream>>>(bigA, hbuf, bigB, wpInWl, inbl, wpInWr,
                                     inna, ingw, wpEW);
  float* zcur = bigB;
  float* spare = bigA;
  for(int l = 0; l < NLAY; ++l){
    const float* zWn = (l < NLAY-1) ? (wpEW + (size_t)(l+1)*12288) : (const float*)nullptr;
    k_layer<<<NTILE, 512, 0, stream>>>(hbuf, zcur, spare, cols,
        eg_eb + l*64, eg_sa + l*192, eg_sb + l*192,
        wpNW + (size_t)l*24576, eg_nb + l*64,
        wpWl + (size_t)l*12288, eg_bl + l*64,
        wpWr + (size_t)l*12288, eg_na + l*192,
        eg_gw + l*640, eg_aa + l*192, eg_ab + l*192,
        zWn, (l==0)?1:2);
    if(l < NLAY-1){ float* t = zcur; zcur = spare; spare = t; }
  }
  k_head <<<BNODES/64, 256, 0, stream>>>(hbuf, wpOW, outb, ong, onb, spare);
  k_pool1<<<256, 192, 0, stream>>>(spare, pp);
  k_pool2<<<8, 192, 0, stream>>>(pp, pooled);
  k_cls  <<<1, 128, 0, stream>>>(pooled, clsW, clsb, (float*)d_out);
}

// Round 11
// 1492.701 us; speedup vs baseline: 1.9087x; 1.9087x over previous
//
#include <hip/hip_runtime.h>
#include <hip/hip_bf16.h>
#include <math.h>

#define EMBC   192
#define NLAY   6
#define IMGC   224
#define FMAPC  56
#define NNODE  3136      // 56*56
#define NBATCH 8
#define BNODES 25088     // NBATCH*NNODE
#define KNNE   8
#define NT     32        // nodes per tile
#define RSQRT2 0.70710678118654752f

__device__ __forceinline__ float sigm(float x){ return 1.0f/(1.0f+__expf(-x)); }

// ---------------- weight repack kernels (run once per launch, tiny) ----------------
// [L][64ch][K][3] -> [L][widx=ch/16][K][16cw][3]  (per-wave 16-ch windows)
__global__ void k_repackw(const float* __restrict__ src, float* __restrict__ dst, int K){
  int l = blockIdx.y;
  size_t S = (size_t)64*K*3;
  int t = blockIdx.x*256 + threadIdx.x;
  if(t < (int)S){
    int j = t % 3; int r = t / 3;
    int cw = r % 16; int m = (r / 16) % K; int widx = r / (16*K);
    dst[l*S + (((size_t)widx*K + m)*16 + cw)*3 + j] =
      src[l*S + ((size_t)(widx*16+cw)*K + m)*3 + j];
  }
}
// [R][K] -> [K][R]
__global__ void k_repack1(const float* __restrict__ src, float* __restrict__ dst,
                          int R, int K){
  int t = blockIdx.x*256 + threadIdx.x;
  if(t < R*K){
    int m = t % K, r = t / K;
    dst[m*R + r] = src[r*K + m];
  }
}

// ---------------- K0: transpose stem_g / (stem_b+pos) to [n][c] ----------------
__global__ void k_tr(const float* __restrict__ g, const float* __restrict__ sb,
                     const float* __restrict__ pe, float* __restrict__ g2,
                     float* __restrict__ pb2){
  int n = blockIdx.x; int c = threadIdx.x;
  g2[n*EMBC + c]  = g[c*NNODE + n];
  pb2[n*EMBC + c] = sb[c*NNODE + n] + pe[c*NNODE + n];
}

// ---------------- K1: stem conv (4x4 stride 4) + LN partial sums ----------------
__global__ __launch_bounds__(256) void k_conv(const float* __restrict__ x,
    const float* __restrict__ cw, const float* __restrict__ cb,
    float* __restrict__ y0, float* __restrict__ parts){
  __shared__ float xs[2688];
  __shared__ float wsh[9216];
  __shared__ float red[512];
  int blk = blockIdx.x; int b = blk / FMAPC; int ph = blk % FMAPC;
  int tid = threadIdx.x;
  for(int t = tid; t < 9216; t += 256) wsh[t] = cw[t];
  for(int t = tid; t < 2688; t += 256){
    int r = t / IMGC; int w = t % IMGC;
    int ci = r >> 2, kh = r & 3;
    xs[t] = x[((size_t)(b*3 + ci)*IMGC + (ph*4 + kh))*IMGC + w];
  }
  __syncthreads();
  float s1 = 0.f, s2 = 0.f;
  for(int oi = tid; oi < FMAPC*EMBC; oi += 256){
    int pw = oi / EMBC; int c = oi % EMBC;
    float acc = cb[c];
    const float4* wv4 = (const float4*)(wsh + c*48);
    #pragma unroll
    for(int r = 0; r < 12; ++r){
      float4 xv = *((const float4*)(xs + r*IMGC + pw*4));
      float4 wv = wv4[r];
      acc += xv.x*wv.x + xv.y*wv.y + xv.z*wv.z + xv.w*wv.w;
    }
    y0[((size_t)(b*NNODE + ph*FMAPC + pw))*EMBC + c] = acc;
    s1 += acc; s2 += acc*acc;
  }
  red[tid] = s1; red[256+tid] = s2;
  __syncthreads();
  for(int st = 128; st > 0; st >>= 1){
    if(tid < st){ red[tid] += red[tid+st]; red[256+tid] += red[256+tid+st]; }
    __syncthreads();
  }
  if(tid == 0){ parts[blk*2] = red[0]; parts[blk*2+1] = red[256]; }
}

// ---------------- K2: finalize per-batch LN stats ----------------
__global__ void k_stats(const float* __restrict__ parts, float* __restrict__ stats){
  int b = threadIdx.x;
  if(b < NBATCH){
    float S = 0.f, Q = 0.f;
    for(int j = 0; j < FMAPC; ++j){ S += parts[(b*FMAPC+j)*2]; Q += parts[(b*FMAPC+j)*2+1]; }
    float cnt = (float)(EMBC*NNODE);
    float mu = S/cnt;
    float var = Q/cnt - mu*mu;
    stats[b*2] = mu; stats[b*2+1] = rsqrtf(var + 1e-5f);
  }
}

// ---------------- K3: LN + pos + embed + mvlin_flat(in_W) -> x_mv ----------------
__global__ __launch_bounds__(256,2) void k_embed(const float* __restrict__ y0,
    const float* __restrict__ stats, const float* __restrict__ g2,
    const float* __restrict__ pb2, const float* __restrict__ inWp,
    const float* __restrict__ inb, const float* __restrict__ coords,
    float* __restrict__ xmv){
  __shared__ float fs[64*193];
  int tid = threadIdx.x, lane = tid & 63;
  int wid = __builtin_amdgcn_readfirstlane(tid >> 6);
  int ch0 = wid << 4;
  int bid = blockIdx.x;
  int blk = (bid & 7)*49 + (bid >> 3);   // 392 = 8*49, XCD-contiguous
  int p0 = blk * 64;
  int b = p0 / NNODE; int n0 = p0 - b*NNODE;
  float mu = stats[b*2], rstd = stats[b*2+1];
  for(int t = tid; t < 64*192; t += 256){
    int n = t / 192, c = t - n*192;
    int nn = n0 + n;
    fs[n*193 + c] = (y0[(size_t)(p0+n)*192 + c] - mu)*rstd*g2[nn*192+c] + pb2[nn*192+c];
  }
  __syncthreads();
  float acc[16];
  #pragma unroll
  for(int ci = 0; ci < 16; ++ci) acc[ci] = 0.f;
  #pragma unroll 2
  for(int m = 0; m < 192; ++m){
    float xm = fs[lane*193 + m];
    const float* wp = inWp + m*64 + ch0;
    #pragma unroll
    for(int ci = 0; ci < 16; ++ci) acc[ci] += wp[ci]*xm;
  }
  float cx = coords[(n0+lane)*2], cy = coords[(n0+lane)*2+1];
  #pragma unroll
  for(int ci = 0; ci < 16; ++ci){
    int ch = ch0 + ci;
    float wc = inWp[192*64 + ch];
    float4 v; v.x = acc[ci] + inb[ch]; v.y = wc*cx; v.z = wc*cy; v.w = 0.f;
    *((float4*)(xmv + ((size_t)(p0+lane)*64 + ch)*4)) = v;
  }
}

// ============ tile helpers (NT=32, 256 threads, 2 nodes/lane) ============
// xs layout: row n of 256 floats; element (n,m,bi) at xs[(n<<8)+(((m+n)&63)<<2)+bi]
__device__ __forceinline__ void stage_x(float* xs, const float* __restrict__ g,
                                        int p0, int tid){
  #pragma unroll
  for(int t = tid; t < NT*64; t += 256){   // 2048 float4
    int n = t >> 6, m = t & 63;
    *((float4*)(xs + (n<<8) + (((m + n)&63)<<2))) =
      *((const float4*)(g + (((size_t)(p0+n))<<8) + (m<<2)));
  }
}
__device__ __forceinline__ void copyout(const float* xs, float* __restrict__ g,
                                        int p0, int tid){
  #pragma unroll
  for(int t = tid; t < NT*64; t += 256){
    int n = t >> 6, m = t & 63;
    float4 v = *((const float4*)(xs + (n<<8) + (((m + n)&63)<<2)));
    *((float4*)(g + (((size_t)(p0+n))<<8) + (m<<2))) = v;
  }
}
// stage one 64-m weight window [4widx][64m][16ch][3] (12288 floats) from packed [widx][K][16][3]
__device__ __forceinline__ void stage_w(float* wst, const float* __restrict__ Wp,
                                        int K, int moff, int tid){
  #pragma unroll
  for(int t = tid; t < 3072; t += 256){    // float4 count; 768 f4 per widx window
    int c = t / 768, r = t - c*768;
    ((float4*)wst)[t] = ((const float4*)(Wp + ((size_t)(c*K + moff)*48)))[r];
  }
}
// dual-node matmul pass over 64 m: pA/pB [4ch][4bl]; wb = widx*3072 + qw*12
__device__ __forceinline__ void mm2n(float (&pA)[4][4], float (&pB)[4][4],
    const float* __restrict__ wst, const float* __restrict__ xrA,
    const float* __restrict__ xrB, int wb, int np){
  #pragma unroll 4
  for(int m = 0; m < 64; ++m){
    float4 xa = *((const float4*)(xrA + (((m + np)&63)<<2)));
    float4 xb = *((const float4*)(xrB + (((m + np + 16)&63)<<2)));
    const float* wp = wst + wb + m*48;
    float4 a = *((const float4*)wp);
    float4 b = *((const float4*)(wp+4));
    float4 c = *((const float4*)(wp+8));
    pA[0][0]+=a.x*xa.x; pA[0][1]+=a.y*xa.y; pA[0][2]+=a.y*xa.z; pA[0][3]+=a.z*xa.w;
    pA[1][0]+=a.w*xa.x; pA[1][1]+=b.x*xa.y; pA[1][2]+=b.x*xa.z; pA[1][3]+=b.y*xa.w;
    pA[2][0]+=b.z*xa.x; pA[2][1]+=b.w*xa.y; pA[2][2]+=b.w*xa.z; pA[2][3]+=c.x*xa.w;
    pA[3][0]+=c.y*xa.x; pA[3][1]+=c.z*xa.y; pA[3][2]+=c.z*xa.z; pA[3][3]+=c.w*xa.w;
    pB[0][0]+=a.x*xb.x; pB[0][1]+=a.y*xb.y; pB[0][2]+=a.y*xb.z; pB[0][3]+=a.z*xb.w;
    pB[1][0]+=a.w*xb.x; pB[1][1]+=b.x*xb.y; pB[1][2]+=b.x*xb.z; pB[1][3]+=b.y*xb.w;
    pB[2][0]+=b.z*xb.x; pB[2][1]+=b.w*xb.y; pB[2][2]+=b.w*xb.z; pB[2][3]+=c.x*xb.w;
    pB[3][0]+=c.y*xb.x; pB[3][1]+=c.z*xb.y; pB[3][2]+=c.z*xb.z; pB[3][3]+=c.w*xb.w;
  }
}
#define ZERO44(A) { _Pragma("unroll") for(int _i=0;_i<4;++_i) _Pragma("unroll") for(int _j=0;_j<4;++_j) A[_i][_j]=0.f; }

// ---------------- K_sgp0: input sgp (mode 0) + fused z0 = eW0 * h ----------------
__global__ __launch_bounds__(256,2) void k_sgp0(const float* __restrict__ src,
    float* __restrict__ h, float* __restrict__ zout,
    const float* __restrict__ Wlp, const float* __restrict__ bl,
    const float* __restrict__ Wrp, const float* __restrict__ na,
    const float* __restrict__ gw, const float* __restrict__ zWp){
  __shared__ float xs[NT*256];    // 32 KB
  __shared__ float wst[12288];    // 48 KB
  int tid = threadIdx.x, lane = tid & 63;
  int widx = __builtin_amdgcn_readfirstlane(tid >> 6);   // 0..3
  int np = lane & 15, qw = lane >> 4;
  int ch0 = widx*16 + qw*4;
  int wb = widx*3072 + qw*12;
  int bid = blockIdx.x;
  int blk = (bid & 7)*98 + (bid >> 3);   // 784 = 8*98
  int p0 = blk * NT;
  const float* xrA = xs + (np<<8);
  const float* xrB = xs + ((np+16)<<8);
  stage_x(xs, src, p0, tid);
  stage_w(wst, Wlp, 64, 0, tid);
  __syncthreads();
  float lA[4][4], lB[4][4];
  ZERO44(lA); ZERO44(lB);
  mm2n(lA, lB, wst, xrA, xrB, wb, np);
  __syncthreads();
  stage_w(wst, Wrp, 64, 0, tid);
  __syncthreads();
  float rA[4][4], rB[4][4];
  ZERO44(rA); ZERO44(rB);
  mm2n(rA, rB, wst, xrA, xrB, wb, np);
  // epilogue (mode 0) for both nodes
  float oA[4][4], oB[4][4];
  #pragma unroll
  for(int j = 0; j < 2; ++j){
    int nn = np + j*16;
    #pragma unroll
    for(int ci = 0; ci < 4; ++ci){
      int ch = ch0 + ci;
      float yr0 = j? rB[ci][0]:rA[ci][0], yr1 = j? rB[ci][1]:rA[ci][1];
      float yr2 = j? rB[ci][2]:rA[ci][2], yr3 = j? rB[ci][3]:rA[ci][3];
      float na0 = sigm(na[ch*3]), na1 = sigm(na[ch*3+1]), na2 = sigm(na[ch*3+2]);
      float d0 = na0*(sqrtf(yr0*yr0 + 1e-12f) - 1.f) + 1.f + 1e-6f;
      float d1 = na1*(sqrtf(yr1*yr1 + yr2*yr2 + 1e-12f) - 1.f) + 1.f + 1e-6f;
      float d2 = na2*(sqrtf(yr3*yr3 + 1e-12f) - 1.f) + 1.f + 1e-6f;
      float xq0 = yr0/d0, xq1 = yr1/d1, xq2 = yr2/d1, xq3 = yr3/d2;
      float4 xv = *((const float4*)(xs + (nn<<8) + (((ch + nn)&63)<<2)));
      const float* gwp = gw + ch*10;
      float gp0 = gwp[0]*xv.x*xq0 + gwp[3]*(xv.y*xq1 + xv.z*xq2) + gwp[7]*xv.w*xq3;
      float gp1 = gwp[1]*xv.x*xq1 + gwp[4]*xv.y*xq0 - gwp[5]*xv.z*xq3 - gwp[8]*xv.w*xq2;
      float gp2 = gwp[1]*xv.x*xq2 + gwp[4]*xv.z*xq0 + gwp[5]*xv.y*xq3 + gwp[8]*xv.w*xq1;
      float gp3 = gwp[2]*xv.x*xq3 + gwp[6]*(xv.y*xq2 - xv.z*xq1) - gwp[9]*xv.w*xq0;
      float l0 = j? lB[ci][0]:lA[ci][0], l1 = j? lB[ci][1]:lA[ci][1];
      float l2 = j? lB[ci][2]:lA[ci][2], l3 = j? lB[ci][3]:lA[ci][3];
      float* o = j? oB[ci] : oA[ci];
      o[0] = (l0 + bl[ch] + gp0)*RSQRT2;
      o[1] = (l1 + gp1)*RSQRT2;
      o[2] = (l2 + gp2)*RSQRT2;
      o[3] = (l3 + gp3)*RSQRT2;
    }
  }
  __syncthreads();
  #pragma unroll
  for(int ci = 0; ci < 4; ++ci){
    int ch = ch0 + ci;
    float4 v0; v0.x=oA[ci][0]; v0.y=oA[ci][1]; v0.z=oA[ci][2]; v0.w=oA[ci][3];
    *((float4*)(xs + (np<<8) + (((ch + np)&63)<<2))) = v0;
    float4 v1; v1.x=oB[ci][0]; v1.y=oB[ci][1]; v1.z=oB[ci][2]; v1.w=oB[ci][3];
    *((float4*)(xs + ((np+16)<<8) + (((ch + np + 16)&63)<<2))) = v1;
  }
  __syncthreads();
  copyout(xs, h, p0, tid);
  stage_w(wst, zWp, 64, 0, tid);
  __syncthreads();
  float zA[4][4], zB[4][4];
  ZERO44(zA); ZERO44(zB);
  mm2n(zA, zB, wst, xrA, xrB, wb, np);
  __syncthreads();
  #pragma unroll
  for(int ci = 0; ci < 4; ++ci){
    int ch = ch0 + ci;
    float4 v0; v0.x=zA[ci][0]; v0.y=zA[ci][1]; v0.z=zA[ci][2]; v0.w=zA[ci][3];
    *((float4*)(xs + (np<<8) + (((ch + np)&63)<<2))) = v0;
    float4 v1; v1.x=zB[ci][0]; v1.y=zB[ci][1]; v1.z=zB[ci][2]; v1.w=zB[ci][3];
    *((float4*)(xs + ((np+16)<<8) + (((ch + np + 16)&63)<<2))) = v1;
  }
  __syncthreads();
  copyout(xs, zout, p0, tid);
}

// ---------------- K_layer: edge-agg + nu + sgp(+silu,+residual) + next z ----------------
__global__ __launch_bounds__(256,2) void k_layer(
    float* __restrict__ h, const float* __restrict__ z,
    float* __restrict__ zout, const int* __restrict__ cols,
    const float* __restrict__ eb, const float* __restrict__ sa,
    const float* __restrict__ sb,
    const float* __restrict__ nWp, const float* __restrict__ nb,
    const float* __restrict__ Wlp, const float* __restrict__ bl,
    const float* __restrict__ Wrp, const float* __restrict__ na,
    const float* __restrict__ gw, const float* __restrict__ aa,
    const float* __restrict__ ab,
    const float* __restrict__ zWp, int mode){
  __shared__ float xs[NT*256];    // 32 KB
  __shared__ float wst[12288];    // 48 KB
  int tid = threadIdx.x, lane = tid & 63;
  int widx = __builtin_amdgcn_readfirstlane(tid >> 6);   // 0..3
  int np = lane & 15, qw = lane >> 4;
  int ch0 = widx*16 + qw*4;
  int wb = widx*3072 + qw*12;
  int bid = blockIdx.x;
  int blk = (bid & 7)*98 + (bid >> 3);   // 784 = 8*98
  int p0 = blk * NT;
  const float* xrA = xs + (np<<8);
  const float* xrB = xs + ((np+16)<<8);
  // ---- phase A: edge aggregation; wave widx owns nodes p0+widx*8..+7; lane = ch
  float ag[8][4];
  {
    int ch = lane;
    float ebv = eb[ch];
    float a0 = sa[ch*3], a1 = sa[ch*3+1], a2 = sa[ch*3+2];
    float b0 = sb[ch*3], b1 = sb[ch*3+1], b2 = sb[ch*3+2];
    #pragma unroll
    for(int e = 0; e < 8; ++e){
      int p = p0 + widx*8 + e;
      float4 zo = *((const float4*)(z + ((size_t)p*64 + ch)*4));
      float ax=0.f, ay=0.f, az_=0.f, aw=0.f;
      #pragma unroll
      for(int k = 0; k < KNNE; ++k){
        int c = cols[p*KNNE + k];
        float4 zc = *((const float4*)(z + ((size_t)c*64 + ch)*4));
        float d0 = zo.x - zc.x + ebv;
        float d1 = zo.y - zc.y;
        float d2 = zo.z - zc.z;
        float d3 = zo.w - zc.w;
        float g0 = sigm(a0*d0 + b0);
        float g1 = sigm(a1*(d1*d1 + d2*d2) + b1);
        float g2v = sigm(a2*(d3*d3) + b2);
        ax += g0*d0; ay += g1*d1; az_ += g1*d2; aw += g2v*d3;
      }
      ag[e][0]=ax; ag[e][1]=ay; ag[e][2]=az_; ag[e][3]=aw;
    }
  }
  // ---- stage h + nu-lo weights; pass1
  stage_x(xs, h, p0, tid);
  stage_w(wst, nWp, 128, 0, tid);
  __syncthreads();                       // B1
  float nuA[4][4], nuB[4][4];
  ZERO44(nuA); ZERO44(nuB);
  mm2n(nuA, nuB, wst, xrA, xrB, wb, np); // nu pass1 (h part)
  float hrA[4][4], hrB[4][4];
  if(mode == 2){
    #pragma unroll
    for(int ci = 0; ci < 4; ++ci){
      int ch = ch0 + ci;
      float4 v0 = *((const float4*)(xrA + (((ch + np)&63)<<2)));
      float4 v1 = *((const float4*)(xrB + (((ch + np + 16)&63)<<2)));
      hrA[ci][0]=v0.x; hrA[ci][1]=v0.y; hrA[ci][2]=v0.z; hrA[ci][3]=v0.w;
      hrB[ci][0]=v1.x; hrB[ci][1]=v1.y; hrB[ci][2]=v1.z; hrB[ci][3]=v1.w;
    }
  }
  __syncthreads();                       // B2
  // agg overwrites xs; stage nu-hi
  #pragma unroll
  for(int e = 0; e < 8; ++e){
    int nn = widx*8 + e;
    float4 v; v.x=ag[e][0]; v.y=ag[e][1]; v.z=ag[e][2]; v.w=ag[e][3];
    *((float4*)(xs + (nn<<8) + (((lane + nn)&63)<<2))) = v;   // lane = ch
  }
  stage_w(wst, nWp, 128, 64, tid);
  __syncthreads();                       // B3
  mm2n(nuA, nuB, wst, xrA, xrB, wb, np); // nu pass2 (agg part)
  __syncthreads();                       // B4
  // nu (with bias) -> xs; stage Wl
  #pragma unroll
  for(int ci = 0; ci < 4; ++ci){
    int ch = ch0 + ci;
    nuA[ci][0] += nb[ch]; nuB[ci][0] += nb[ch];
    float4 v0; v0.x=nuA[ci][0]; v0.y=nuA[ci][1]; v0.z=nuA[ci][2]; v0.w=nuA[ci][3];
    *((float4*)(xs + (np<<8) + (((ch + np)&63)<<2))) = v0;
    float4 v1; v1.x=nuB[ci][0]; v1.y=nuB[ci][1]; v1.z=nuB[ci][2]; v1.w=nuB[ci][3];
    *((float4*)(xs + ((np+16)<<8) + (((ch + np + 16)&63)<<2))) = v1;
  }
  stage_w(wst, Wlp, 64, 0, tid);
  __syncthreads();                       // B5
  float lA[4][4], lB[4][4];
  ZERO44(lA); ZERO44(lB);
  mm2n(lA, lB, wst, xrA, xrB, wb, np);
  __syncthreads();                       // B6
  stage_w(wst, Wrp, 64, 0, tid);
  __syncthreads();                       // B7
  float rA[4][4], rB[4][4];
  ZERO44(rA); ZERO44(rB);
  mm2n(rA, rB, wst, xrA, xrB, wb, np);
  // ---- epilogue: normalize, gp (x = nu regs), silu, residual — both nodes
  float oA[4][4], oB[4][4];
  #pragma unroll
  for(int j = 0; j < 2; ++j){
    #pragma unroll
    for(int ci = 0; ci < 4; ++ci){
      int ch = ch0 + ci;
      float yr0 = j? rB[ci][0]:rA[ci][0], yr1 = j? rB[ci][1]:rA[ci][1];
      float yr2 = j? rB[ci][2]:rA[ci][2], yr3 = j? rB[ci][3]:rA[ci][3];
      float na0 = sigm(na[ch*3]), na1 = sigm(na[ch*3+1]), na2 = sigm(na[ch*3+2]);
      float d0 = na0*(sqrtf(yr0*yr0 + 1e-12f) - 1.f) + 1.f + 1e-6f;
      float d1 = na1*(sqrtf(yr1*yr1 + yr2*yr2 + 1e-12f) - 1.f) + 1.f + 1e-6f;
      float d2 = na2*(sqrtf(yr3*yr3 + 1e-12f) - 1.f) + 1.f + 1e-6f;
      float xq0 = yr0/d0, xq1 = yr1/d1, xq2 = yr2/d1, xq3 = yr3/d2;
      float x0 = j? nuB[ci][0]:nuA[ci][0], x1 = j? nuB[ci][1]:nuA[ci][1];
      float x2 = j? nuB[ci][2]:nuA[ci][2], x3 = j? nuB[ci][3]:nuA[ci][3];
      const float* gwp = gw + ch*10;
      float gp0 = gwp[0]*x0*xq0 + gwp[3]*(x1*xq1 + x2*xq2) + gwp[7]*x3*xq3;
      float gp1 = gwp[1]*x0*xq1 + gwp[4]*x1*xq0 - gwp[5]*x2*xq3 - gwp[8]*x3*xq2;
      float gp2 = gwp[1]*x0*xq2 + gwp[4]*x2*xq0 + gwp[5]*x1*xq3 + gwp[8]*x3*xq1;
      float gp3 = gwp[2]*x0*xq3 + gwp[6]*(x1*xq2 - x2*xq1) - gwp[9]*x3*xq0;
      float l0 = j? lB[ci][0]:lA[ci][0], l1 = j? lB[ci][1]:lA[ci][1];
      float l2 = j? lB[ci][2]:lA[ci][2], l3 = j? lB[ci][3]:lA[ci][3];
      float o0 = (l0 + bl[ch] + gp0)*RSQRT2;
      float o1 = (l1 + gp1)*RSQRT2;
      float o2 = (l2 + gp2)*RSQRT2;
      float o3 = (l3 + gp3)*RSQRT2;
      float g0 = sigm(aa[ch*3]*o0 + ab[ch*3]);
      float g1 = sigm(aa[ch*3+1]*(o1*o1 + o2*o2) + ab[ch*3+1]);
      float g2v = sigm(aa[ch*3+2]*(o3*o3) + ab[ch*3+2]);
      float v0 = g0*o0, v1 = g1*o1, v2 = g1*o2, v3 = g2v*o3;
      if(mode == 2){
        if(j){ v0 += hrB[ci][0]; v1 += hrB[ci][1]; v2 += hrB[ci][2]; v3 += hrB[ci][3]; }
        else { v0 += hrA[ci][0]; v1 += hrA[ci][1]; v2 += hrA[ci][2]; v3 += hrA[ci][3]; }
      }
      float* o = j? oB[ci] : oA[ci];
      o[0]=v0; o[1]=v1; o[2]=v2; o[3]=v3;
    }
  }
  __syncthreads();                       // B8
  #pragma unroll
  for(int ci = 0; ci < 4; ++ci){
    int ch = ch0 + ci;
    float4 v0; v0.x=oA[ci][0]; v0.y=oA[ci][1]; v0.z=oA[ci][2]; v0.w=oA[ci][3];
    *((float4*)(xs + (np<<8) + (((ch + np)&63)<<2))) = v0;
    float4 v1; v1.x=oB[ci][0]; v1.y=oB[ci][1]; v1.z=oB[ci][2]; v1.w=oB[ci][3];
    *((float4*)(xs + ((np+16)<<8) + (((ch + np + 16)&63)<<2))) = v1;
  }
  __syncthreads();                       // B9
  copyout(xs, h, p0, tid);
  // ---- z_next = zW * h_new
  if(zWp != nullptr){
    stage_w(wst, zWp, 64, 0, tid);
    __syncthreads();                     // B10
    float zA[4][4], zB[4][4];
    ZERO44(zA); ZERO44(zB);
    mm2n(zA, zB, wst, xrA, xrB, wb, np);
    __syncthreads();                     // B11
    #pragma unroll
    for(int ci = 0; ci < 4; ++ci){
      int ch = ch0 + ci;
      float4 v0; v0.x=zA[ci][0]; v0.y=zA[ci][1]; v0.z=zA[ci][2]; v0.w=zA[ci][3];
      *((float4*)(xs + (np<<8) + (((ch + np)&63)<<2))) = v0;
      float4 v1; v1.x=zB[ci][0]; v1.y=zB[ci][1]; v1.z=zB[ci][2]; v1.w=zB[ci][3];
      *((float4*)(xs + ((np+16)<<8) + (((ch + np + 16)&63)<<2))) = v1;
    }
    __syncthreads();                     // B12
    copyout(xs, zout, p0, tid);
  }
}

// ---------------- K9: head projection (blade 0) + per-node LN ----------------
__global__ __launch_bounds__(256,2) void k_head(const float* __restrict__ h,
    const float* __restrict__ oWp, const float* __restrict__ ob,
    const float* __restrict__ ong, const float* __restrict__ onb,
    float* __restrict__ s){
  __shared__ float hs[64*65];
  __shared__ float rr[512];
  int tid = threadIdx.x, lane = tid & 63;
  int wid = __builtin_amdgcn_readfirstlane(tid >> 6);
  int c0 = wid*48;
  int bid = blockIdx.x;
  int blk = (bid & 7)*49 + (bid >> 3);   // 392 = 8*49
  int p0 = blk * 64;
  for(int t = tid; t < 64*64; t += 256){
    int nn = t >> 6, c = t & 63;
    hs[nn*65 + c] = h[(((size_t)(p0+nn))*64 + c)*4];
  }
  __syncthreads();
  float a[48];
  #pragma unroll
  for(int ci = 0; ci < 48; ++ci) a[ci] = 0.f;
  #pragma unroll 2
  for(int m = 0; m < 64; ++m){
    float xm = hs[lane*65 + m];
    const float* wp = oWp + m*192 + c0;
    #pragma unroll
    for(int ci = 0; ci < 48; ++ci) a[ci] += wp[ci]*xm;
  }
  float s1 = 0.f, s2 = 0.f;
  #pragma unroll
  for(int ci = 0; ci < 48; ++ci){
    a[ci] += ob[c0+ci];
    s1 += a[ci]; s2 += a[ci]*a[ci];
  }
  rr[wid*64 + lane] = s1; rr[256 + wid*64 + lane] = s2;
  __syncthreads();
  float S = rr[lane] + rr[64+lane] + rr[128+lane] + rr[192+lane];
  float Q = rr[256+lane] + rr[320+lane] + rr[384+lane] + rr[448+lane];
  float mu = S*(1.0f/EMBC);
  float var = Q*(1.0f/EMBC) - mu*mu;
  float rstd = rsqrtf(var + 1e-5f);
  #pragma unroll
  for(int q = 0; q < 12; ++q){
    int c = c0 + q*4;
    float4 v;
    v.x = (a[q*4  ] - mu)*rstd*ong[c  ] + onb[c  ];
    v.y = (a[q*4+1] - mu)*rstd*ong[c+1] + onb[c+1];
    v.z = (a[q*4+2] - mu)*rstd*ong[c+2] + onb[c+2];
    v.w = (a[q*4+3] - mu)*rstd*ong[c+3] + onb[c+3];
    *((float4*)(s + (size_t)(p0+lane)*192 + c)) = v;
  }
}

// ---------------- K10: pooling (two-stage, deterministic) ----------------
__global__ void k_pool1(const float* __restrict__ s, float* __restrict__ pp){
  int blk = blockIdx.x;
  int b = blk >> 5, chunk = blk & 31;
  int c = threadIdx.x;
  float acc = 0.f;
  int n0 = chunk*98;
  for(int j = 0; j < 98; ++j) acc += s[((size_t)(b*NNODE + n0 + j))*EMBC + c];
  pp[(size_t)blk*EMBC + c] = acc;
}
__global__ void k_pool2(const float* __restrict__ pp, float* __restrict__ pooled){
  int b = blockIdx.x; int c = threadIdx.x;
  float acc = 0.f;
  for(int j = 0; j < 32; ++j) acc += pp[((size_t)(b*32 + j))*EMBC + c];
  pooled[b*EMBC + c] = acc * (1.0f/NNODE);
}

// ---------------- K11: classifier ----------------
__global__ void k_cls(const float* __restrict__ pooled, const float* __restrict__ cW,
                      const float* __restrict__ cb, float* __restrict__ out){
  int tid = threadIdx.x;
  if(tid < NBATCH*10){
    int b = tid/10, k = tid%10;
    float acc = cb[k];
    for(int c = 0; c < EMBC; ++c) acc += pooled[b*EMBC + c]*cW[k*EMBC + c];
    out[tid] = acc;
  }
}

extern "C" void kernel_launch(void* const* d_in, const int* in_sizes, int n_in,
                              void* d_out, int out_size, void* d_ws, size_t ws_size,
                              hipStream_t stream){
  const float* x      = (const float*)d_in[0];
  const float* conv_w = (const float*)d_in[1];
  const float* conv_b = (const float*)d_in[2];
  const float* stem_g = (const float*)d_in[3];
  const float* stem_b = (const float*)d_in[4];
  const float* pos_e  = (const float*)d_in[5];
  const float* coords = (const float*)d_in[6];
  const float* inW    = (const float*)d_in[7];
  const float* inb    = (const float*)d_in[8];
  const float* inWl   = (const float*)d_in[9];
  const float* inbl   = (const float*)d_in[10];
  const float* inWr   = (const float*)d_in[11];
  const float* inna   = (const float*)d_in[12];
  const float* ingw   = (const float*)d_in[13];
  const float* eg_eW  = (const float*)d_in[14];
  const float* eg_eb  = (const float*)d_in[15];
  const float* eg_sa  = (const float*)d_in[16];
  const float* eg_sb  = (const float*)d_in[17];
  const float* eg_nW  = (const float*)d_in[18];
  const float* eg_nb  = (const float*)d_in[19];
  const float* eg_Wl  = (const float*)d_in[20];
  const float* eg_bl  = (const float*)d_in[21];
  const float* eg_Wr  = (const float*)d_in[22];
  const float* eg_na  = (const float*)d_in[23];
  const float* eg_gw  = (const float*)d_in[24];
  const float* eg_aa  = (const float*)d_in[25];
  const float* eg_ab  = (const float*)d_in[26];
  const float* outW   = (const float*)d_in[27];
  const float* outb   = (const float*)d_in[28];
  const float* ong    = (const float*)d_in[29];
  const float* onb    = (const float*)d_in[30];
  const float* clsW   = (const float*)d_in[31];
  const float* clsb   = (const float*)d_in[32];
  const int*   cols   = (const int*)d_in[34];   // rows[p*8+k] == p by construction

  float* ws = (float*)d_ws;
  size_t off = 0;
  float* hbuf  = ws + off; off += (size_t)BNODES*256;   // h
  float* bigA  = ws + off; off += (size_t)BNODES*256;   // x_mv / z ping
  float* bigB  = ws + off; off += (size_t)BNODES*256;   // y0 (stem) then z pong
  float* g2    = ws + off; off += (size_t)NNODE*EMBC;
  float* pb2   = ws + off; off += (size_t)NNODE*EMBC;
  float* parts = ws + off; off += 896;
  float* stats = ws + off; off += 16;
  float* pp    = ws + off; off += 256*EMBC;
  float* pooled= ws + off; off += NBATCH*EMBC;
  // packed weights
  float* wpInW = ws + off; off += 193*64;
  float* wpOW  = ws + off; off += 64*192;
  float* wpInWl= ws + off; off += 12288;
  float* wpInWr= ws + off; off += 12288;
  float* wpEW  = ws + off; off += (size_t)NLAY*12288;
  float* wpWl  = ws + off; off += (size_t)NLAY*12288;
  float* wpWr  = ws + off; off += (size_t)NLAY*12288;
  float* wpNW  = ws + off; off += (size_t)NLAY*24576;
  float* y0    = bigB;   // stem output aliases bigB (dead before first z write)

  const int NTILE = BNODES/NT;   // 784

  // ---- weight repacks ----
  { dim3 g1((12352+255)/256); k_repack1<<<g1, 256, 0, stream>>>(inW,  wpInW, 64, 193); }
  { dim3 g1((12288+255)/256); k_repack1<<<g1, 256, 0, stream>>>(outW, wpOW, 192, 64); }
  { dim3 g3((12288+255)/256, 1); k_repackw<<<g3, 256, 0, stream>>>(inWl, wpInWl, 64); }
  { dim3 g3((12288+255)/256, 1); k_repackw<<<g3, 256, 0, stream>>>(inWr, wpInWr, 64); }
  { dim3 g3((12288+255)/256, NLAY); k_repackw<<<g3, 256, 0, stream>>>(eg_eW, wpEW, 64); }
  { dim3 g3((12288+255)/256, NLAY); k_repackw<<<g3, 256, 0, stream>>>(eg_Wl, wpWl, 64); }
  { dim3 g3((12288+255)/256, NLAY); k_repackw<<<g3, 256, 0, stream>>>(eg_Wr, wpWr, 64); }
  { dim3 g3((24576+255)/256, NLAY); k_repackw<<<g3, 256, 0, stream>>>(eg_nW, wpNW, 128); }

  k_tr   <<<NNODE, 192, 0, stream>>>(stem_g, stem_b, pos_e, g2, pb2);
  k_conv <<<NBATCH*FMAPC, 256, 0, stream>>>(x, conv_w, conv_b, y0, parts);
  k_stats<<<1, 64, 0, stream>>>(parts, stats);
  k_embed<<<BNODES/64, 256, 0, stream>>>(y0, stats, g2, pb2, wpInW, inb, coords, bigA);
  k_sgp0 <<<NTILE, 256, 0, stream>>>(bigA, hbuf, bigB, wpInWl, inbl, wpInWr,
                                     inna, ingw, wpEW);
  float* zcur = bigB;
  float* spare = bigA;
  for(int l = 0; l < NLAY; ++l){
    const float* zWn = (l < NLAY-1) ? (wpEW + (size_t)(l+1)*12288) : (const float*)nullptr;
    k_layer<<<NTILE, 256, 0, stream>>>(hbuf, zcur, spare, cols,
        eg_eb + l*64, eg_sa + l*192, eg_sb + l*192,
        wpNW + (size_t)l*24576, eg_nb + l*64,
        wpWl + (size_t)l*12288, eg_bl + l*64,
        wpWr + (size_t)l*12288, eg_na + l*192,
        eg_gw + l*640, eg_aa + l*192, eg_ab + l*192,
        zWn, (l==0)?1:2);
    if(l < NLAY-1){ float* t = zcur; zcur = spare; spare = t; }
  }
  k_head <<<BNODES/64, 256, 0, stream>>>(hbuf, wpOW, outb, ong, onb, spare);
  k_pool1<<<256, 192, 0, stream>>>(spare, pp);
  k_pool2<<<8, 192, 0, stream>>>(pp, pooled);
  k_cls  <<<1, 128, 0, stream>>>(pooled, clsW, clsb, (float*)d_out);
}